// Round 2
// baseline (444.889 us; speedup 1.0000x reference)
//
#include <hip/hip_runtime.h>

typedef unsigned short u16;
typedef __bf16 bf16x8 __attribute__((ext_vector_type(8)));
typedef float f32x4 __attribute__((ext_vector_type(4)));

typedef __attribute__((address_space(1))) const void* as1_cvp;
typedef __attribute__((address_space(3))) void* as3_vp;

// ---------- bf16 helpers ----------
__device__ __forceinline__ float b2f(u16 u) {
  union { unsigned int i; float f; } x; x.i = ((unsigned int)u) << 16; return x.f;
}
__device__ __forceinline__ u16 f2b(float f) {
  union { float f; unsigned int i; } x; x.f = f;
  unsigned int u = x.i;
  u += 0x7fffu + ((u >> 16) & 1u);   // round-to-nearest-even
  return (u16)(u >> 16);
}

// ---------- dtype detector: flag=1 if inputs are fp32, 0 if bf16 ----------
__global__ void k_detect(const u16* __restrict__ x, int* __restrict__ flag) {
  int t = threadIdx.x;
  int sane = 0;
#pragma unroll
  for (int i = 0; i < 8; ++i) {
    u16 u = x[t * 8 + i];
    int e = (u >> 7) & 0xFF;
    sane += (u == 0 || (e >= 100 && e <= 150)) ? 1 : 0;
  }
#pragma unroll
  for (int off = 32; off >= 1; off >>= 1) sane += __shfl_xor(sane, off);
  if (t == 0) *flag = (sane < 480) ? 1 : 0;
}

// ---------- x -> bf16 downconvert; no-op when inputs already bf16 ----------
__global__ void k_convert(const void* __restrict__ xin, u16* __restrict__ xb,
                          const int* __restrict__ flagp) {
  if (!*flagp) return;  // bf16 inputs: GEMM1 reads raw input directly
  long i = ((long)blockIdx.x * 256 + threadIdx.x) * 4;
  float4 v = *(const float4*)((const float*)xin + i);
  u16* o = xb + i;
  o[0] = f2b(v.x); o[1] = f2b(v.y); o[2] = f2b(v.z); o[3] = f2b(v.w);
}

// ---------- W[K][N] -> WT[N][K] as bf16 ----------
__global__ void k_transpose(const void* __restrict__ W, u16* __restrict__ WT,
                            const int* __restrict__ flagp, int K, int N) {
  __shared__ u16 tile[32][33];
  int f = *flagp;
  int n0 = blockIdx.x * 32, k0 = blockIdx.y * 32;
  int tx = threadIdx.x, ty = threadIdx.y;
#pragma unroll
  for (int i = 0; i < 32; i += 8) {
    long idx = (long)(k0 + ty + i) * N + n0 + tx;
    tile[ty + i][tx] = f ? f2b(((const float*)W)[idx]) : ((const u16*)W)[idx];
  }
  __syncthreads();
#pragma unroll
  for (int i = 0; i < 32; i += 8)
    WT[(long)(n0 + ty + i) * K + k0 + tx] = tile[tx][ty + i];
}

// ---------- bias in MFMA C-fragment order, bf16, mask baked in ----------
__global__ void k_biasfrag(const int* __restrict__ rel, const void* __restrict__ table,
                           u16* __restrict__ biasFrag, const int* __restrict__ flagp) {
  int t = blockIdx.x * 256 + threadIdx.x;   // 57344 total
  int f = *flagp;
  int ln = t & 63, r2 = t >> 6;
  int tj = r2 & 7, r3 = r2 >> 3;
  int ti = r3 % 7, h = r3 / 7;
  int col = ln & 15, qrow = ln >> 4;
  int j = tj * 16 + col;
  u16 v[4];
#pragma unroll
  for (int r = 0; r < 4; ++r) {
    int i = ti * 16 + qrow * 4 + r; if (i > 97) i = 97;
    float val;
    if (j < 98) {
      int rr = rel[i * 98 + j];
      val = f ? ((const float*)table)[rr * 16 + h] : b2f(((const u16*)table)[rr * 16 + h]);
    } else {
      val = -1e30f;
    }
    v[r] = f2b(val);
  }
  ushort4 out; out.x = v[0]; out.y = v[1]; out.z = v[2]; out.w = v[3];
  *(ushort4*)(biasFrag + (long)t * 4) = out;
}

// ================= 256x256 bf16 GEMM, 3-barrier K-tile, 2-ahead staging ======
// C[M][N] = A[M][K] * BT[N][K]^T + bias.  8 waves, BK=64, 128KiB LDS dbuf.
// LDS layout per matrix: [buf(2)][half(2)][row(128)][chunk16B(8)], XOR swizzle
// chunk ^= (row&7): linear global_load_lds dest + inverse-swizzled per-lane
// GLOBAL source, swizzled ds_read addresses (rule 21).
// K-tile schedule (stages 2 K-tiles ahead; same-parity buffer is legal because
// each stage lands only after its half's last CU-wide reader barrier):
//   S0: 16 ds_read (af[0-3], bfr[0-3]) ; MFMA(0,0) ; lgkm0 ; BAR1
//   S1: 8 ds_read (af[4-7]) ; STAGE B0,B1(kt+2) ; MFMA(0,2) ; MFMA(4,0) ; lgkm0 ; BAR2
//   S2: STAGE A0,A1(kt+2) ; vmcnt(8) [confirms all of kt+1] ; BAR3 ; MFMA(4,2)
// vmcnt(8) leaves exactly kt+2's 8 loads in flight; kt+1's loads get a full
// K-tile period of latency cover.  Requires M%256==0, N%256==0, K%64==0,
// K/64>=3, grid%8==0.
#define MFMA_Q(M0, N0)                                                         \
  __builtin_amdgcn_s_setprio(1);                                               \
  _Pragma("unroll") for (int kk = 0; kk < 2; ++kk)                             \
  _Pragma("unroll") for (int mi = 0; mi < 4; ++mi)                             \
  _Pragma("unroll") for (int ni = 0; ni < 2; ++ni)                             \
      acc[(M0) + mi][(N0) + ni] = __builtin_amdgcn_mfma_f32_16x16x32_bf16(     \
          afr[(M0) + mi][kk], bfr[(N0) + ni][kk], acc[(M0) + mi][(N0) + ni],   \
          0, 0, 0);                                                            \
  __builtin_amdgcn_s_setprio(0);

#define STAGE(arr, bufi, half, src, kt) do {                                   \
    u16* _d = &arr[(bufi) * 16384 + (half) * 8192 + w * 512];                  \
    const u16* _s = (src) + (long)(half) * 128 * K + (long)(kt) * 64;          \
    __builtin_amdgcn_global_load_lds((as1_cvp)(const void*)_s, (as3_vp)_d, 16, 0, 0); \
    __builtin_amdgcn_global_load_lds((as1_cvp)(const void*)(_s + 64L * K),     \
                                     (as3_vp)(_d + 4096), 16, 0, 0);           \
  } while (0)

__global__ __launch_bounds__(512, 2) void k_gemm256(
    const u16* __restrict__ A_raw, const u16* __restrict__ A_conv,
    const u16* __restrict__ BT, const void* __restrict__ bias, void* __restrict__ C,
    const int* __restrict__ flagp, int N, int K, int out_follows_flag, int NBY) {
  __shared__ __align__(16) u16 As[32768];   // 64 KiB
  __shared__ __align__(16) u16 Bs[32768];   // 64 KiB
  const int f = *flagp;
  const u16* A = f ? A_conv : A_raw;
  const int t = threadIdx.x, w = t >> 6, ln = t & 63;
  // T1: XCD-aware chunked swizzle (grid%8==0), bx-major so A panels reuse in L2
  const int nwg = gridDim.x, cpx = nwg >> 3;
  const int wg = (blockIdx.x & 7) * cpx + (blockIdx.x >> 3);
  const long bm = (long)(wg / NBY) * 256, bn = (long)(wg % NBY) * 256;
  const int NK = K >> 6;
  // wave -> output subtile
  const int wm = w >> 2, wn = w & 3, bh = wn >> 1, bq = wn & 1;
  const int col = ln & 15, qrow = ln >> 4, cx = ln & 7;
  // staging role: row srow(+64 for 2nd inst,+half*128), chunk inverse-swizzled
  const int srow = w * 8 + (ln >> 3);
  const int schunk = (ln & 7) ^ ((ln >> 3) & 7);
  const u16* aS = A + (bm + srow) * (long)K + schunk * 8;
  const u16* bS = BT + (bn + srow) * (long)K + schunk * 8;
  // swizzled ds_read bases / k-offsets
  const u16* aRd = &As[wm * 8192 + col * 64];
  const u16* bRd = &Bs[bh * 8192 + bq * 4096 + col * 64];
  const int ko0 = (qrow ^ cx) * 8;         // kk=0 chunk
  const int ko1 = ((4 + qrow) ^ cx) * 8;   // kk=1 chunk
  // bias loads pinned BEFORE prologue stages (keeps vmcnt accounting exact:
  // they are older than every STAGE, so the first vmcnt(8) retires them too)
  float bv[4];
#pragma unroll
  for (int ni = 0; ni < 4; ++ni) {
    long c = bn + wn * 64 + ni * 16 + col;
    bv[ni] = f ? ((const float*)bias)[c] : b2f(((const u16*)bias)[c]);
  }
  asm volatile("" ::: "memory");
  // prologue: stage kt0 and kt1 completely (16 loads/wave, 128KB/CU in flight)
  STAGE(Bs, 0, 0, bS, 0); STAGE(Bs, 0, 1, bS, 0);
  STAGE(As, 0, 0, aS, 0); STAGE(As, 0, 1, aS, 0);
  STAGE(Bs, 1, 0, bS, 1); STAGE(Bs, 1, 1, bS, 1);
  STAGE(As, 1, 0, aS, 1); STAGE(As, 1, 1, aS, 1);
  asm volatile("s_waitcnt vmcnt(8)" ::: "memory");   // kt0 done, kt1 in flight
  __builtin_amdgcn_s_barrier();

  f32x4 acc[8][4] = {};
  bf16x8 afr[8][2], bfr[4][2];
  for (int kt = 0; kt < NK; ++kt) {
    const int buf = kt & 1;
    const u16* aP = aRd + buf * 16384;
    const u16* bP = bRd + buf * 16384;
    // ---- S0: A-low + all B fragments; first MFMA quadrant ----
#pragma unroll
    for (int i = 0; i < 4; ++i) {
      afr[i][0] = *(const bf16x8*)(aP + i * 1024 + ko0);
      afr[i][1] = *(const bf16x8*)(aP + i * 1024 + ko1);
      bfr[i][0] = *(const bf16x8*)(bP + i * 1024 + ko0);
      bfr[i][1] = *(const bf16x8*)(bP + i * 1024 + ko1);
    }
    MFMA_Q(0, 0)
    asm volatile("s_waitcnt lgkmcnt(0)" ::: "memory");  // all S0 reads landed
    __builtin_amdgcn_s_barrier();                       // BAR1: B-stage now safe
    // ---- S1: A-high reads + B(kt+2) stage under a 32-MFMA cluster ----
#pragma unroll
    for (int i = 0; i < 4; ++i) {
      afr[4 + i][0] = *(const bf16x8*)(aP + (i + 4) * 1024 + ko0);
      afr[4 + i][1] = *(const bf16x8*)(aP + (i + 4) * 1024 + ko1);
    }
    if (kt + 2 < NK) { STAGE(Bs, buf, 0, bS, kt + 2); STAGE(Bs, buf, 1, bS, kt + 2); }
    MFMA_Q(0, 2)
    MFMA_Q(4, 0)
    asm volatile("s_waitcnt lgkmcnt(0)" ::: "memory");  // af[4-7] landed
    __builtin_amdgcn_s_barrier();                       // BAR2: A-stage now safe
    // ---- S2: A(kt+2) stage; confirm kt+1; publish; last MFMA quadrant ----
    if (kt + 2 < NK) {
      STAGE(As, buf, 0, aS, kt + 2); STAGE(As, buf, 1, aS, kt + 2);
      asm volatile("s_waitcnt vmcnt(8)" ::: "memory");  // kt+1 fully staged
    } else if (kt + 1 < NK) {
      asm volatile("s_waitcnt vmcnt(0)" ::: "memory");
    }
    __builtin_amdgcn_s_barrier();                       // BAR3: publish kt+1
    MFMA_Q(4, 2)
  }
  // ---- epilogue ----
  const int of = out_follows_flag ? f : 0;
#pragma unroll
  for (int mi = 0; mi < 8; ++mi)
#pragma unroll
    for (int ni = 0; ni < 4; ++ni)
#pragma unroll
      for (int r = 0; r < 4; ++r) {
        long row = bm + wm * 128 + mi * 16 + qrow * 4 + r;
        long c = bn + wn * 64 + ni * 16 + col;
        float v = acc[mi][ni][r] + bv[ni];
        if (of) ((float*)C)[row * N + c] = v;
        else    ((u16*)C)[row * N + c] = f2b(v);
      }
}

// ---------- fused window attention v2: one block per (b,h), 4 waves ----------
__global__ __launch_bounds__(256) void k_attn(
    const u16* __restrict__ qkv, const u16* __restrict__ biasFrag,
    u16* __restrict__ attnout) {
  __shared__ __align__(16) u16 Qs[112 * 32];     // aliased as Os after compute
  __shared__ __align__(16) u16 Ks[128 * 32];
  __shared__ __align__(16) u16 Vt[32 * 136];
  __shared__ __align__(16) u16 Ps[4][16 * 136];  // per-wave slot
  const int b = blockIdx.x, h = blockIdx.y;
  const int t = threadIdx.x, w = t >> 6, ln = t & 63;
  const u16* qbase = qkv + (long)b * 98 * 1536 + h * 32;
  {
    const int gr = ln >> 2, gc = (ln & 3) * 8;
    for (int n = w; n < 7; n += 4) {
      int g = n * 16 + gr; if (g > 97) g = 97;
      __builtin_amdgcn_global_load_lds((as1_cvp)(const void*)(qbase + (long)g * 1536 + gc),
                                       (as3_vp)(Qs + n * 512), 16, 0, 0);
    }
    for (int n = w; n < 8; n += 4) {
      int g = n * 16 + gr; if (g > 97) g = 97;
      __builtin_amdgcn_global_load_lds((as1_cvp)(const void*)(qbase + 512 + (long)g * 1536 + gc),
                                       (as3_vp)(Ks + n * 512), 16, 0, 0);
    }
  }
  for (int z = t; z < 32 * 19; z += 256) {
    int d = z / 19, q = z % 19;
    *(unsigned int*)&Vt[d * 136 + 98 + q * 2] = 0u;
  }
  for (int idx = t; idx < 784; idx += 256) {
    int i = idx >> 3, c4 = (idx & 7) * 4;
    ushort4 v4 = *(const ushort4*)(qbase + 1024 + (long)i * 1536 + c4);
    Vt[(c4 + 0) * 136 + i] = v4.x;
    Vt[(c4 + 1) * 136 + i] = v4.y;
    Vt[(c4 + 2) * 136 + i] = v4.z;
    Vt[(c4 + 3) * 136 + i] = v4.w;
  }
  __syncthreads();
  const int col = ln & 15, qrow = ln >> 4;
  const float scale = 0.17677669529663687f;  // 32^-0.5
  u16* Psw = &Ps[w][0];
  f32x4 o[2][2] = {{{0.f,0.f,0.f,0.f},{0.f,0.f,0.f,0.f}},{{0.f,0.f,0.f,0.f},{0.f,0.f,0.f,0.f}}};
  for (int tt = 0; tt < 2; ++tt) {
    const int ti = w + tt * 4;
    if (ti >= 7) break;
    const u16* bp = biasFrag + ((long)((h * 7 + ti) * 8) * 64 + ln) * 4;
    ushort4 bfv[8];
#pragma unroll
    for (int tj = 0; tj < 8; ++tj) bfv[tj] = *(const ushort4*)(bp + tj * 256);
    bf16x8 aq = *(const bf16x8*)&Qs[(ti * 16 + col) * 32 + qrow * 8];
    f32x4 s[8];
#pragma unroll
    for (int tj = 0; tj < 8; ++tj) {
      bf16x8 bk = *(const bf16x8*)&Ks[(tj * 16 + col) * 32 + qrow * 8];
      f32x4 z = {0.f, 0.f, 0.f, 0.f};
      s[tj] = __builtin_amdgcn_mfma_f32_16x16x32_bf16(aq, bk, z, 0, 0, 0);
    }
#pragma unroll
    for (int r = 0; r < 4; ++r) {
      float vals[8]; float m = -1e30f;
#pragma unroll
      for (int tj = 0; tj < 8; ++tj) {
        u16 bb = (r == 0) ? bfv[tj].x : (r == 1) ? bfv[tj].y : (r == 2) ? bfv[tj].z : bfv[tj].w;
        float v = fmaf(s[tj][r], scale, b2f(bb));
        vals[tj] = v; m = fmaxf(m, v);
      }
#pragma unroll
      for (int off = 1; off < 16; off <<= 1) m = fmaxf(m, __shfl_xor(m, off));
      float sum = 0.f;
#pragma unroll
      for (int tj = 0; tj < 8; ++tj) { vals[tj] = __expf(vals[tj] - m); sum += vals[tj]; }
#pragma unroll
      for (int off = 1; off < 16; off <<= 1) sum += __shfl_xor(sum, off);
      float inv = 1.f / sum;
      const int rt = qrow * 4 + r;
#pragma unroll
      for (int tj = 0; tj < 8; ++tj)
        Psw[rt * 136 + tj * 16 + col] = f2b(vals[tj] * inv);
    }
#pragma unroll
    for (int ks = 0; ks < 4; ++ks) {
      bf16x8 ap  = *(const bf16x8*)&Psw[col * 136 + ks * 32 + qrow * 8];
      bf16x8 bv0 = *(const bf16x8*)&Vt[col * 136 + ks * 32 + qrow * 8];
      bf16x8 bv1 = *(const bf16x8*)&Vt[(16 + col) * 136 + ks * 32 + qrow * 8];
      o[tt][0] = __builtin_amdgcn_mfma_f32_16x16x32_bf16(ap, bv0, o[tt][0], 0, 0, 0);
      o[tt][1] = __builtin_amdgcn_mfma_f32_16x16x32_bf16(ap, bv1, o[tt][1], 0, 0, 0);
    }
  }
  __syncthreads();
  u16* Os = Qs;
#pragma unroll
  for (int tt = 0; tt < 2; ++tt) {
    const int ti = w + tt * 4;
    if (ti >= 7) continue;
#pragma unroll
    for (int r = 0; r < 4; ++r) {
      const int i = ti * 16 + qrow * 4 + r;
      if (i < 98) {
        Os[i * 32 + col]      = f2b(o[tt][0][r]);
        Os[i * 32 + 16 + col] = f2b(o[tt][1][r]);
      }
    }
  }
  __syncthreads();
  u16* obase = attnout + (long)b * 98 * 512 + h * 32;
  for (int idx = t; idx < 784; idx += 256) {
    int i = idx >> 3, c4 = (idx & 7) * 4;
    *(ushort4*)(obase + (long)i * 512 + c4) = *(const ushort4*)&Os[i * 32 + c4];
  }
}

extern "C" void kernel_launch(void* const* d_in, const int* in_sizes, int n_in,
                              void* d_out, int out_size, void* d_ws, size_t ws_size,
                              hipStream_t stream) {
  (void)in_sizes; (void)n_in; (void)out_size; (void)ws_size;
  char* p = (char*)d_ws;
  u16* qkvbuf   = (u16*)p;  p += 50176L * 1536 * 2;   // 154,140,672
  u16* attnbuf  = (u16*)p;  u16* xb = attnbuf; p += 50176L * 512 * 2;  // 51,380,224
  u16* wqkvT    = (u16*)p;  p += 1536L * 512 * 2;     // 1,572,864
  u16* wprojT   = (u16*)p;  p += 512L * 512 * 2;      // 524,288
  u16* biasFrag = (u16*)p;  p += 57344L * 4 * 2;      // 458,752
  int* flagp    = (int*)p;

  k_detect<<<1, 64, 0, stream>>>((const u16*)d_in[0], flagp);
  k_convert<<<25088, 256, 0, stream>>>(d_in[0], xb, flagp);
  k_transpose<<<dim3(48, 16), dim3(32, 8), 0, stream>>>(d_in[1], wqkvT, flagp, 512, 1536);
  k_transpose<<<dim3(16, 16), dim3(32, 8), 0, stream>>>(d_in[3], wprojT, flagp, 512, 512);
  k_biasfrag<<<224, 256, 0, stream>>>((const int*)d_in[6], d_in[5], biasFrag, flagp);
  // qkv = x @ qkv_w + qkv_b   [50176 x 1536], 196x6 tiles of 256^2
  k_gemm256<<<dim3(196 * 6), 512, 0, stream>>>((const u16*)d_in[0], xb, wqkvT, d_in[2],
                                               qkvbuf, flagp, 1536, 512, 0, 6);
  // attention -> attnbuf [50176 x 512]
  k_attn<<<dim3(512, 16), 256, 0, stream>>>(qkvbuf, biasFrag, attnbuf);
  // out = attnbuf @ proj_w + proj_b   [50176 x 512], 196x2 tiles of 256^2
  k_gemm256<<<dim3(196 * 2), 512, 0, stream>>>(attnbuf, attnbuf, wprojT, d_in[4],
                                               d_out, flagp, 512, 512, 1, 2);
}